// Round 18
// baseline (213.367 us; speedup 1.0000x reference)
//
#include <hip/hip_runtime.h>
#include <math.h>

#define T_STEPS 500
#define BATCH   64
#define S_DIM   64
#define A_DIM   16
#define OBS_D   32
#define CTL_D   8
#define H_DIM   30

#define CHUNKS   8
#define CHUNK_L  63      // 8*63 = 504 >= 500
#define BURN     8
#define MAXSTEPS (CHUNK_L + BURN)   // 71

#define LOG2PI 1.8378770664093453f

typedef _Float16 v2h __attribute__((ext_vector_type(2)));
typedef __fp16  fp16x2 __attribute__((ext_vector_type(2)));

__device__ __forceinline__ float wmax(float v){
  #pragma unroll
  for (int o = 32; o > 0; o >>= 1) v = fmaxf(v, __shfl_xor(v, o, 64));
  return v;
}
__device__ __forceinline__ float wsum(float v){
  #pragma unroll
  for (int o = 32; o > 0; o >>= 1) v += __shfl_xor(v, o, 64);
  return v;
}

template<int CTRL>
__device__ __forceinline__ float dpp_add(float v){
  int x = __builtin_amdgcn_update_dpp(0, __float_as_int(v), CTRL, 0xF, 0xF, true);
  return v + __int_as_float(x);
}
__device__ __forceinline__ v2h u2h(unsigned int x){
  union { unsigned int u; v2h h; } c; c.u = x; return c.h;
}
__device__ __forceinline__ unsigned int pack_pkrtz(float a, float b){
  union { fp16x2 h; unsigned int u; } c;
  c.h = __builtin_amdgcn_cvt_pkrtz(a, b);
  return c.u;
}

// raw barrier: drain LDS/SMEM only — global loads/stores (vmcnt) stay in flight
#define BAR() do { \
  asm volatile("s_waitcnt lgkmcnt(0)" ::: "memory"); \
  __builtin_amdgcn_s_barrier(); \
  asm volatile("" ::: "memory"); \
  __builtin_amdgcn_sched_barrier(0); \
} while (0)

#define FOR16(X) X(0) X(1) X(2) X(3) X(4) X(5) X(6) X(7) X(8) X(9) X(10) X(11) X(12) X(13) X(14) X(15)

// ---------------- k_front: logp_o (bx<8000) + Bp^T f16 softmax (<8256) + logp_u/p_a (<8381) ----------------
__global__ __launch_bounds__(256) void k_front(const float* __restrict__ o,
                                               const float* __restrict__ obs_mu,
                                               const float* __restrict__ obs_lv,
                                               const float* __restrict__ obs_tl,
                                               const float* __restrict__ Blog,
                                               const float* __restrict__ u,
                                               const float* __restrict__ ctl_mu,
                                               const float* __restrict__ ctl_lv,
                                               const float* __restrict__ ctl_tl,
                                               float* __restrict__ lo_out,
                                               _Float16* __restrict__ Bph,
                                               float* __restrict__ lup,
                                               float* __restrict__ pap){
  const int bx  = blockIdx.x;
  const int tid = threadIdx.x;

  if (bx < 8000){
    const int k = bx & 63;
    const float* __restrict__ Lk  = obs_tl + k * OBS_D * OBS_D;
    const float* __restrict__ muk = obs_mu + k * OBS_D;
    const float* __restrict__ lvk = obs_lv + k * OBS_D;

    float dinv[OBS_D];
    float lvsum = 0.f;
    #pragma unroll
    for (int i = 0; i < OBS_D; ++i){
      float x = lvk[i];
      lvsum += x;
      dinv[i] = __expf(-x);
    }

    const int item = (bx >> 6) * 256 + tid;   // 125*256 = 32000
    const float* op = o + item * OBS_D;
    float d[OBS_D];
    #pragma unroll
    for (int i = 0; i < OBS_D; i += 4){
      float4 v = *(const float4*)(op + i);
      d[i]   = v.x - muk[i];
      d[i+1] = v.y - muk[i+1];
      d[i+2] = v.z - muk[i+2];
      d[i+3] = v.w - muk[i+3];
    }
    float z[OBS_D];
    float acc = 0.f;
    #pragma unroll
    for (int i = 0; i < OBS_D; ++i){
      float s0 = d[i], s1 = 0.f;
      #pragma unroll
      for (int jj = 0; jj + 1 < i; jj += 2){
        s0 = fmaf(-Lk[i * OBS_D + jj],     z[jj],     s0);
        s1 = fmaf(-Lk[i * OBS_D + jj + 1], z[jj + 1], s1);
      }
      if (i & 1) s0 = fmaf(-Lk[i * OBS_D + i - 1], z[i - 1], s0);
      float zz = (s0 + s1) * dinv[i];
      z[i] = zz;
      acc  = fmaf(zz, zz, acc);
    }
    lo_out[item * S_DIM + k] = -0.5f * acc - lvsum - 0.5f * OBS_D * LOG2PI;
    return;
  }

  if (bx < 8256){
    // ---- Bp softmax rows, stored TRANSPOSED f16: Bph[a][j][s] ----
    const int row  = (bx - 8000) * 4 + (tid >> 6);   // row = a*64 + s
    const int lane = tid & 63;                        // lane = j
    float v = Blog[row * 64 + lane];
    float m = wmax(v);
    float e = __expf(v - m);
    float s = wsum(e);
    const int a  = row >> 6;
    const int ss = row & 63;
    Bph[(a * 64 + lane) * 64 + ss] = (_Float16)(e / s);
    return;
  }

  // ---- logp_u + p_a ----
  const int item = (bx - 8256) * 256 + tid;   // 125*256 = 32000
  const float* up = u + item * CTL_D;
  float uu[CTL_D];
  #pragma unroll
  for (int i = 0; i < CTL_D; i += 4){
    float4 v = *(const float4*)(up + i);
    uu[i] = v.x; uu[i+1] = v.y; uu[i+2] = v.z; uu[i+3] = v.w;
  }
  float lp[A_DIM];
  #pragma unroll
  for (int a = 0; a < A_DIM; ++a){
    float z[CTL_D];
    float acc = 0.f, lvs = 0.f;
    #pragma unroll
    for (int i = 0; i < CTL_D; ++i){
      float lvv = ctl_lv[a * CTL_D + i];
      lvs += lvv;
      float s = uu[i] - ctl_mu[a * CTL_D + i];
      #pragma unroll
      for (int jj = 0; jj < i; ++jj) s = fmaf(-ctl_tl[a * 64 + i * CTL_D + jj], z[jj], s);
      z[i] = s * __expf(-lvv);
      acc  = fmaf(z[i], z[i], acc);
    }
    lp[a] = -0.5f * acc - lvs - 0.5f * CTL_D * LOG2PI;
  }
  float m = -1e30f;
  #pragma unroll
  for (int a = 0; a < A_DIM; ++a) m = fmaxf(m, lp[a]);
  float e[A_DIM], se = 0.f;
  #pragma unroll
  for (int a = 0; a < A_DIM; ++a){ e[a] = __expf(lp[a] - m); se += e[a]; }
  float inv = 1.f / se;
  #pragma unroll
  for (int a = 0; a < A_DIM; ++a){
    lup[item * A_DIM + a] = lp[a];
    pap[item * A_DIM + a] = e[a] * inv;
  }
}

// ---------------- k_vi: 1024 threads, 1 (a,s) row per thread ----------------
__global__ __launch_bounds__(1024, 1) void k_vi(const float* __restrict__ Blog,
                                                const float* __restrict__ obs_lv,
                                                const float* __restrict__ Clog,
                                                const float* __restrict__ tau,
                                                float* __restrict__ Qout){
  const int tid  = threadIdx.x;
  const int lane = tid & 63;
  __shared__ __align__(16) float Vs[S_DIM];
  __shared__ __align__(16) float Qlds[A_DIM][S_DIM];
  __shared__ float hs[H_DIM];

  float c  = Clog[lane];
  float cm = wmax(c);
  float cs = wsum(__expf(c - cm));
  float lseC = cm + __logf(cs);
  float sumLnCp = wsum(c) - 64.f * lseC;

  if (tid < 64){
    float t0   = tau[0];
    float rate = __expf(t0);
    float lg = 0.f;
    for (int i = 2; i <= lane; ++i) lg += __logf((float)i);
    float lh = (lane < H_DIM) ? ((float)lane * t0 - rate - lg) : -1e30f;
    float m  = wmax(lh);
    float e  = (lane < H_DIM) ? __expf(lh - m) : 0.f;
    float s  = wsum(e);
    if (lane < H_DIM) hs[lane] = e / s;
  }

  const int r = tid;               // a*64 + s
  const int a = r >> 6, s = r & 63;
  const float* p = Blog + r * 64;
  float4 raw[16];
  float mr = -1e30f;
  #pragma unroll
  for (int q = 0; q < 16; ++q){
    float4 v = *(const float4*)(p + 4 * q);
    raw[q] = v;
    mr = fmaxf(mr, fmaxf(fmaxf(v.x, v.y), fmaxf(v.z, v.w)));
  }
  float ssum = 0.f, dot = 0.f;
  #pragma unroll
  for (int q = 0; q < 16; ++q){
    float4 v = raw[q];
    float4 e;
    e.x = __expf(v.x - mr); e.y = __expf(v.y - mr);
    e.z = __expf(v.z - mr); e.w = __expf(v.w - mr);
    ssum += (e.x + e.y) + (e.z + e.w);
    dot  += e.x * (v.x - mr) + e.y * (v.y - mr) + e.z * (v.z - mr) + e.w * (v.w - mr);
    raw[q] = e;
  }
  float inv = 1.f / ssum;
  float lns = __logf(ssum);
  #pragma unroll
  for (int q = 0; q < 16; ++q){
    float4 e = raw[q];
    raw[q] = make_float4(e.x * inv, e.y * inv, e.z * inv, e.w * inv);
  }
  float negent = dot * inv - lns;

  float oe = 0.f;
  const float* lvp = obs_lv + s * OBS_D;
  #pragma unroll
  for (int dd = 0; dd < OBS_D; dd += 4){
    float4 v = *(const float4*)(lvp + dd);
    oe += v.x + v.y + v.z + v.w;
  }
  oe += 0.5f * OBS_D * (1.f + LOG2PI);
  float R  = -negent + sumLnCp - oe;
  float Qc = R;
  __syncthreads();
  float Qa = hs[0] * R;

  for (int it = 1; it < H_DIM; ++it){
    Qlds[a][s] = Qc;
    __syncthreads();
    if (tid < 64){
      float m = -1e30f;
      #pragma unroll
      for (int aa = 0; aa < A_DIM; ++aa) m = fmaxf(m, Qlds[aa][lane]);
      float sv = 0.f;
      #pragma unroll
      for (int aa = 0; aa < A_DIM; ++aa) sv += __expf(Qlds[aa][lane] - m);
      Vs[lane] = m + __logf(sv);
    }
    __syncthreads();
    float hw = hs[it];
    float accA = 0.f, accB = 0.f;
    #pragma unroll
    for (int q = 0; q < 16; ++q){
      float4 v = *(const float4*)(&Vs[4 * q]);
      accA = fmaf(raw[q].x, v.x, fmaf(raw[q].y, v.y, accA));
      accB = fmaf(raw[q].z, v.z, fmaf(raw[q].w, v.w, accB));
    }
    Qc = R + accA + accB;
    Qa = fmaf(hw, Qc, Qa);
  }
  Qout[r] = Qa;
}

// ---------------- k_scan: time-chunked speculative scan, 8 chunks x 64 batch = 512 blocks ----------------
// Chunk c outputs t in [63c, min(500,63c+63)); c>0 burns in 8 steps from a uniform belief.
// Inner product via v_pk_fma_f16 (full-rate) instead of quarter-rate v_dot2.
// Lane layout: so = lane&7 (s-octant), jj = lane>>3, j = 8*wave + jj.
__global__ __launch_bounds__(512, 4)
void k_scan(const _Float16* __restrict__ Bph,
            const float* __restrict__ lo,
            const float* __restrict__ pa,
            const float* __restrict__ Dlog,
            float* __restrict__ bseq){
  const int n   = blockIdx.x;
  const int c   = blockIdx.y;
  const int tid = threadIdx.x;
  const int g   = tid >> 6;
  const int l   = tid & 63;
  const int so  = l & 7;
  const int jj  = l >> 3;
  const int j   = g * 8 + jj;

  const int t_out0  = c * CHUNK_L;
  const int t_end   = (t_out0 + CHUNK_L < T_STEPS) ? (t_out0 + CHUNK_L) : T_STEPS;
  const int t_start = (c == 0) ? 0 : (t_out0 - BURN);
  const int nsteps  = t_end - t_start;   // 63 (c=0), 71 (1..6), 67 (c=7)

  __shared__ __align__(16) float lik_lds[MAXSTEPS][S_DIM];   // 18176 B
  __shared__ __align__(16) unsigned int b16[2][32];          // belief as f16 pairs
  __shared__ __align__(16) unsigned short ps16[2][8];        // per-wave partial sums, f16

  // ---- f16 Bp tile: Tq{A} = Bph[A][j][8so .. 8so+7]  (8 halves = uint4) ----
  #define DECLT(A) uint4 Tq##A;
  FOR16(DECLT)
  #define LOADT(A) Tq##A = *(const uint4*)(Bph + ((A) * 4096 + j * 64 + 8 * so));
  FOR16(LOADT)
  #define PINT(A) asm volatile("" : "+v"(Tq##A.x), "+v"(Tq##A.y), "+v"(Tq##A.z), "+v"(Tq##A.w));
  FOR16(PINT)

  // ---- prologue: stage lik rows [t_start, t_start+nsteps) into LDS (coalesced) ----
  const float* lo_n = lo + n * 64;     // + t*4096 + col
  const float* pa_n = pa + n * 16;     // + t*1024 + a (block-uniform -> scalar loads)
  for (int i = tid; i < nsteps * 64; i += 512){
    int r = i >> 6, col = i & 63;
    lik_lds[r][col] = lo_n[(t_start + r) * 4096 + col];
  }
  if (tid < 64){
    // chunk 0: true b0 = softmax(Dlog); others: uniform (softmax of zeros)
    float dl = (c == 0) ? Dlog[l] : 0.f;
    float m = wmax(dl);
    float e = __expf(dl - m);
    float s = wsum(e);
    float b0 = e / s;
    if (c == 0) bseq[n * 64 + l] = b0;
    float nb = __shfl_xor(b0, 1, 64);
    if (!(l & 1)) b16[0][l >> 1] = pack_pkrtz(b0, nb);
  }
  if (tid < 8) ps16[0][tid] = 0x3000;   // f16(0.125): 8 wave-partials sum to 1
  __syncthreads();

  for (int r = g; r < nsteps; r += 8){
    float v = lik_lds[r][l];
    float m = wmax(v);
    lik_lds[r][l] = __expf(v - m);
  }
  __syncthreads();

  // pa double-buffered scalar prefetch
  #define DECLPA(A) float pac_##A, pan_##A;
  FOR16(DECLPA)
  const float* pp0 = pa_n + t_start * 1024;
  #define LDPA0(A) pac_##A = pp0[A];
  FOR16(LDPA0)

  int cur = 0;
  for (int tt = 0; tt < nsteps; ++tt){
    const int t   = t_start + tt;
    const int nxt = cur ^ 1;

    // ---- prefetch pa[t+1] (scalar/SMEM; lands before BAR drain) ----
    const int t1 = (t + 1 < T_STEPS) ? (t + 1) : (T_STEPS - 1);
    const float* pp1 = pa_n + t1 * 1024;
    #define LDPAN(A) pan_##A = pp1[A];
    FOR16(LDPAN)

    // ---- per-step LDS reads ----
    float likr = lik_lds[tt][j];
    uint4 q = *(const uint4*)&ps16[cur][0];
    v2h a01 = u2h(q.x) + u2h(q.y);
    v2h a23 = u2h(q.z) + u2h(q.w);
    v2h aa  = a01 + a23;
    float sum = (float)aa.x + (float)aa.y;
    float lik = likr * __builtin_amdgcn_rcpf(sum);

    // ---- belief octant (8 f16 = one uint4, 8-way same-address broadcast) ----
    uint4 bq = *(const uint4*)&b16[cur][so * 4];
    v2h bh0 = u2h(bq.x), bh1 = u2h(bq.y), bh2 = u2h(bq.z), bh3 = u2h(bq.w);

    float pr0 = 0.f, pr1 = 0.f, pr2 = 0.f, pr3 = 0.f;
    // v_pk_fma_f16 chain (full-rate) + f32 combine per action
    #define DOTQ(A, P) { \
      v2h acc2 = __builtin_elementwise_fma(u2h(Tq##A.x), bh0, (v2h)(_Float16)0); \
      acc2 = __builtin_elementwise_fma(u2h(Tq##A.y), bh1, acc2); \
      acc2 = __builtin_elementwise_fma(u2h(Tq##A.z), bh2, acc2); \
      acc2 = __builtin_elementwise_fma(u2h(Tq##A.w), bh3, acc2); \
      float y = (float)acc2.x + (float)acc2.y; \
      P = fmaf(pac_##A, y, P); }
    DOTQ(0,  pr0) DOTQ(1,  pr1) DOTQ(2,  pr2) DOTQ(3,  pr3)
    DOTQ(4,  pr0) DOTQ(5,  pr1) DOTQ(6,  pr2) DOTQ(7,  pr3)
    DOTQ(8,  pr0) DOTQ(9,  pr1) DOTQ(10, pr2) DOTQ(11, pr3)
    DOTQ(12, pr0) DOTQ(13, pr1) DOTQ(14, pr2) DOTQ(15, pr3)
    float pri = (pr0 + pr1) + (pr2 + pr3);

    // butterfly over s-octants — all lanes get full prior[j]
    pri = dpp_add<0xB1>(pri);    // quad_perm xor1
    pri = dpp_add<0x4E>(pri);    // quad_perm xor2
    pri = dpp_add<0x141>(pri);   // row_half_mirror (xor7)

    float post = pri * lik;
    if (t >= t_out0){            // only own outputs (burn-in suppressed)
      if (so == 0)
        bseq[(t + 1) * 4096 + n * 64 + j] = post;   // fire-and-forget (vmcnt, survives BAR)
    }

    // pack (post_j, post_{j+1}) -> b16[nxt] from lanes l%16==0
    {
      int x = __builtin_amdgcn_update_dpp(0, __float_as_int(post), 0x128, 0xF, 0xF, true); // row_ror:8
      if (!(l & 15)) b16[nxt][g * 4 + (l >> 4)] = pack_pkrtz(post, __int_as_float(x));
    }

    // per-wave sum of post -> ps16[nxt] (f16; any block-uniform scale works — k_out renormalizes)
    {
      float w = post;
      w = dpp_add<0x128>(w);
      w = dpp_add<0x142>(w);
      w = dpp_add<0x143>(w);
      if (l == 48) ps16[nxt][g] = (unsigned short)(pack_pkrtz(w, 0.f) & 0xffffu);
    }

    // rotate pa
    #define CPPA(A) pac_##A = pan_##A;
    FOR16(CPPA)

    BAR();
    cur = nxt;
  }
}

// ---------------- epilogue: logp_pi + logp_obs, fully parallel over (t,n) ----------------
__global__ __launch_bounds__(256, 1) void k_out(const float* __restrict__ bseq,
                                                const float* __restrict__ Qg,
                                                const float* __restrict__ lo,
                                                const float* __restrict__ lu,
                                                float* __restrict__ out){
  __shared__ __align__(16) float Qs[A_DIM][S_DIM];
  const int tid = threadIdx.x;
  for (int i = tid; i < A_DIM * S_DIM; i += 256) Qs[i >> 6][i & 63] = Qg[i];
  __syncthreads();

  const int item = blockIdx.x * 256 + tid;   // t*64 + n
  float bs[64];
  const float* bp_ = bseq + item * 64;
  float bsum = 0.f;
  #pragma unroll
  for (int i = 0; i < 16; ++i){
    float4 v = *(const float4*)(bp_ + 4 * i);
    bs[4*i] = v.x; bs[4*i+1] = v.y; bs[4*i+2] = v.z; bs[4*i+3] = v.w;
    bsum += (v.x + v.y) + (v.z + v.w);
  }
  float binv = 1.0f / bsum;

  float G[A_DIM];
  #pragma unroll
  for (int a = 0; a < A_DIM; ++a){
    float acc = 0.f;
    #pragma unroll
    for (int s = 0; s < 64; ++s) acc = fmaf(bs[s], Qs[a][s], acc);
    G[a] = acc * binv;
  }
  const float* lup = lu + item * A_DIM;
  float m1 = -1e30f, m0 = -1e30f;
  float x1[A_DIM];
  #pragma unroll
  for (int a = 0; a < A_DIM; ++a){
    x1[a] = G[a] + lup[a];
    m1 = fmaxf(m1, x1[a]);
    m0 = fmaxf(m0, G[a]);
  }
  float e1 = 0.f, e0 = 0.f;
  #pragma unroll
  for (int a = 0; a < A_DIM; ++a){
    e1 += __expf(x1[a] - m1);
    e0 += __expf(G[a] - m0);
  }
  out[item] = (m1 + __logf(e1)) - (m0 + __logf(e0));

  // logp_obs: uses b[t+1] and lo[t]
  const float* bq = bseq + (item + 64) * 64;
  float bsum2 = 0.f;
  #pragma unroll
  for (int i = 0; i < 16; ++i){
    float4 v = *(const float4*)(bq + 4 * i);
    bs[4*i] = v.x; bs[4*i+1] = v.y; bs[4*i+2] = v.z; bs[4*i+3] = v.w;
    bsum2 += (v.x + v.y) + (v.z + v.w);
  }
  float inv2 = 1.0f / bsum2;
  const float* lop = lo + item * 64;
  float terms[64];
  float mt = -1e30f;
  #pragma unroll
  for (int i = 0; i < 16; ++i){
    float4 v = *(const float4*)(lop + 4 * i);
    float t0 = __logf(bs[4*i]   * inv2 + 1e-6f) * v.x;
    float t1 = __logf(bs[4*i+1] * inv2 + 1e-6f) * v.y;
    float t2 = __logf(bs[4*i+2] * inv2 + 1e-6f) * v.z;
    float t3 = __logf(bs[4*i+3] * inv2 + 1e-6f) * v.w;
    terms[4*i] = t0; terms[4*i+1] = t1; terms[4*i+2] = t2; terms[4*i+3] = t3;
    mt = fmaxf(mt, fmaxf(fmaxf(t0, t1), fmaxf(t2, t3)));
  }
  float es = 0.f;
  #pragma unroll
  for (int s = 0; s < 64; ++s) es += __expf(terms[s] - mt);
  out[T_STEPS * BATCH + item] = mt + __logf(es);
}

extern "C" void kernel_launch(void* const* d_in, const int* in_sizes, int n_in,
                              void* d_out, int out_size, void* d_ws, size_t ws_size,
                              hipStream_t stream){
  const float* o      = (const float*)d_in[0];
  const float* u      = (const float*)d_in[1];
  const float* obs_mu = (const float*)d_in[2];
  const float* obs_lv = (const float*)d_in[3];
  const float* obs_tl = (const float*)d_in[4];
  const float* ctl_mu = (const float*)d_in[5];
  const float* ctl_lv = (const float*)d_in[6];
  const float* ctl_tl = (const float*)d_in[7];
  const float* Blog   = (const float*)d_in[8];
  const float* Dlog   = (const float*)d_in[9];
  const float* Clog   = (const float*)d_in[10];
  const float* tau    = (const float*)d_in[11];
  float* out = (float*)d_out;
  float* ws  = (float*)d_ws;

  _Float16* Bph = (_Float16*)ws;       // 65536 halves = 32768 f32 slots ([a][j][s])
  float* Q    = ws + 32768;            // 1024
  float* lo   = ws + 33792;            // 2,048,000
  float* lu   = ws + 2081792;          // 512,000
  float* pa   = ws + 2593792;          // 512,000
  float* bseq = ws + 3105792;          // 501*4096 = 2,052,096   (total ~20.6 MiB)

  k_front<<<8381, 256, 0, stream>>>(o, obs_mu, obs_lv, obs_tl, Blog,
                                    u, ctl_mu, ctl_lv, ctl_tl, lo, Bph, lu, pa);
  k_vi   <<<1, 1024, 0, stream>>>(Blog, obs_lv, Clog, tau, Q);
  k_scan <<<dim3(64, CHUNKS), 512, 0, stream>>>(Bph, lo, pa, Dlog, bseq);
  k_out  <<<125, 256, 0, stream>>>(bseq, Q, lo, lu, out);
}

// Round 19
// 192.027 us; speedup vs baseline: 1.1111x; 1.1111x over previous
//
#include <hip/hip_runtime.h>
#include <math.h>

#define T_STEPS 500
#define BATCH   64
#define S_DIM   64
#define A_DIM   16
#define OBS_D   32
#define CTL_D   8
#define H_DIM   30

#define CHUNKS   8
#define CHUNK_L  63      // 8*63 = 504 >= 500
#define BURN     8
#define MAXSTEPS (CHUNK_L + BURN)   // 71

#define LOG2PI 1.8378770664093453f

typedef _Float16 v2h __attribute__((ext_vector_type(2)));
typedef __fp16  fp16x2 __attribute__((ext_vector_type(2)));

__device__ __forceinline__ float wmax(float v){
  #pragma unroll
  for (int o = 32; o > 0; o >>= 1) v = fmaxf(v, __shfl_xor(v, o, 64));
  return v;
}
__device__ __forceinline__ float wsum(float v){
  #pragma unroll
  for (int o = 32; o > 0; o >>= 1) v += __shfl_xor(v, o, 64);
  return v;
}

template<int CTRL>
__device__ __forceinline__ float dpp_add(float v){
  int x = __builtin_amdgcn_update_dpp(0, __float_as_int(v), CTRL, 0xF, 0xF, true);
  return v + __int_as_float(x);
}
__device__ __forceinline__ v2h u2h(unsigned int x){
  union { unsigned int u; v2h h; } c; c.u = x; return c.h;
}
__device__ __forceinline__ unsigned int pack_pkrtz(float a, float b){
  union { fp16x2 h; unsigned int u; } c;
  c.h = __builtin_amdgcn_cvt_pkrtz(a, b);
  return c.u;
}

// raw barrier: drain LDS/SMEM only — global loads/stores (vmcnt) stay in flight
#define BAR() do { \
  asm volatile("s_waitcnt lgkmcnt(0)" ::: "memory"); \
  __builtin_amdgcn_s_barrier(); \
  asm volatile("" ::: "memory"); \
  __builtin_amdgcn_sched_barrier(0); \
} while (0)

#define FOR16(X) X(0) X(1) X(2) X(3) X(4) X(5) X(6) X(7) X(8) X(9) X(10) X(11) X(12) X(13) X(14) X(15)

// ---------------- k_front: logp_o (bx<8000) + Bp^T f16 softmax (<8256) + logp_u/p_a (<8381) ----------------
__global__ __launch_bounds__(256) void k_front(const float* __restrict__ o,
                                               const float* __restrict__ obs_mu,
                                               const float* __restrict__ obs_lv,
                                               const float* __restrict__ obs_tl,
                                               const float* __restrict__ Blog,
                                               const float* __restrict__ u,
                                               const float* __restrict__ ctl_mu,
                                               const float* __restrict__ ctl_lv,
                                               const float* __restrict__ ctl_tl,
                                               float* __restrict__ lo_out,
                                               _Float16* __restrict__ Bph,
                                               float* __restrict__ lup,
                                               float* __restrict__ pap){
  const int bx  = blockIdx.x;
  const int tid = threadIdx.x;

  if (bx < 8000){
    const int k = bx & 63;
    const float* __restrict__ Lk  = obs_tl + k * OBS_D * OBS_D;
    const float* __restrict__ muk = obs_mu + k * OBS_D;
    const float* __restrict__ lvk = obs_lv + k * OBS_D;

    float dinv[OBS_D];
    float lvsum = 0.f;
    #pragma unroll
    for (int i = 0; i < OBS_D; ++i){
      float x = lvk[i];
      lvsum += x;
      dinv[i] = __expf(-x);
    }

    const int item = (bx >> 6) * 256 + tid;   // 125*256 = 32000
    const float* op = o + item * OBS_D;
    float d[OBS_D];
    #pragma unroll
    for (int i = 0; i < OBS_D; i += 4){
      float4 v = *(const float4*)(op + i);
      d[i]   = v.x - muk[i];
      d[i+1] = v.y - muk[i+1];
      d[i+2] = v.z - muk[i+2];
      d[i+3] = v.w - muk[i+3];
    }
    float z[OBS_D];
    float acc = 0.f;
    #pragma unroll
    for (int i = 0; i < OBS_D; ++i){
      float s0 = d[i], s1 = 0.f;
      #pragma unroll
      for (int jj = 0; jj + 1 < i; jj += 2){
        s0 = fmaf(-Lk[i * OBS_D + jj],     z[jj],     s0);
        s1 = fmaf(-Lk[i * OBS_D + jj + 1], z[jj + 1], s1);
      }
      if (i & 1) s0 = fmaf(-Lk[i * OBS_D + i - 1], z[i - 1], s0);
      float zz = (s0 + s1) * dinv[i];
      z[i] = zz;
      acc  = fmaf(zz, zz, acc);
    }
    lo_out[item * S_DIM + k] = -0.5f * acc - lvsum - 0.5f * OBS_D * LOG2PI;
    return;
  }

  if (bx < 8256){
    // ---- Bp softmax rows, stored TRANSPOSED f16: Bph[a][j][s] ----
    const int row  = (bx - 8000) * 4 + (tid >> 6);   // row = a*64 + s
    const int lane = tid & 63;                        // lane = j
    float v = Blog[row * 64 + lane];
    float m = wmax(v);
    float e = __expf(v - m);
    float s = wsum(e);
    const int a  = row >> 6;
    const int ss = row & 63;
    Bph[(a * 64 + lane) * 64 + ss] = (_Float16)(e / s);
    return;
  }

  // ---- logp_u + p_a ----
  const int item = (bx - 8256) * 256 + tid;   // 125*256 = 32000
  const float* up = u + item * CTL_D;
  float uu[CTL_D];
  #pragma unroll
  for (int i = 0; i < CTL_D; i += 4){
    float4 v = *(const float4*)(up + i);
    uu[i] = v.x; uu[i+1] = v.y; uu[i+2] = v.z; uu[i+3] = v.w;
  }
  float lp[A_DIM];
  #pragma unroll
  for (int a = 0; a < A_DIM; ++a){
    float z[CTL_D];
    float acc = 0.f, lvs = 0.f;
    #pragma unroll
    for (int i = 0; i < CTL_D; ++i){
      float lvv = ctl_lv[a * CTL_D + i];
      lvs += lvv;
      float s = uu[i] - ctl_mu[a * CTL_D + i];
      #pragma unroll
      for (int jj = 0; jj < i; ++jj) s = fmaf(-ctl_tl[a * 64 + i * CTL_D + jj], z[jj], s);
      z[i] = s * __expf(-lvv);
      acc  = fmaf(z[i], z[i], acc);
    }
    lp[a] = -0.5f * acc - lvs - 0.5f * CTL_D * LOG2PI;
  }
  float m = -1e30f;
  #pragma unroll
  for (int a = 0; a < A_DIM; ++a) m = fmaxf(m, lp[a]);
  float e[A_DIM], se = 0.f;
  #pragma unroll
  for (int a = 0; a < A_DIM; ++a){ e[a] = __expf(lp[a] - m); se += e[a]; }
  float inv = 1.f / se;
  #pragma unroll
  for (int a = 0; a < A_DIM; ++a){
    lup[item * A_DIM + a] = lp[a];
    pap[item * A_DIM + a] = e[a] * inv;
  }
}

// ---------------- k_vi: 1024 threads, 1 (a,s) row per thread ----------------
__global__ __launch_bounds__(1024, 1) void k_vi(const float* __restrict__ Blog,
                                                const float* __restrict__ obs_lv,
                                                const float* __restrict__ Clog,
                                                const float* __restrict__ tau,
                                                float* __restrict__ Qout){
  const int tid  = threadIdx.x;
  const int lane = tid & 63;
  __shared__ __align__(16) float Vs[S_DIM];
  __shared__ __align__(16) float Qlds[A_DIM][S_DIM];
  __shared__ float hs[H_DIM];

  float c  = Clog[lane];
  float cm = wmax(c);
  float cs = wsum(__expf(c - cm));
  float lseC = cm + __logf(cs);
  float sumLnCp = wsum(c) - 64.f * lseC;

  if (tid < 64){
    float t0   = tau[0];
    float rate = __expf(t0);
    float lg = 0.f;
    for (int i = 2; i <= lane; ++i) lg += __logf((float)i);
    float lh = (lane < H_DIM) ? ((float)lane * t0 - rate - lg) : -1e30f;
    float m  = wmax(lh);
    float e  = (lane < H_DIM) ? __expf(lh - m) : 0.f;
    float s  = wsum(e);
    if (lane < H_DIM) hs[lane] = e / s;
  }

  const int r = tid;               // a*64 + s
  const int a = r >> 6, s = r & 63;
  const float* p = Blog + r * 64;
  float4 raw[16];
  float mr = -1e30f;
  #pragma unroll
  for (int q = 0; q < 16; ++q){
    float4 v = *(const float4*)(p + 4 * q);
    raw[q] = v;
    mr = fmaxf(mr, fmaxf(fmaxf(v.x, v.y), fmaxf(v.z, v.w)));
  }
  float ssum = 0.f, dot = 0.f;
  #pragma unroll
  for (int q = 0; q < 16; ++q){
    float4 v = raw[q];
    float4 e;
    e.x = __expf(v.x - mr); e.y = __expf(v.y - mr);
    e.z = __expf(v.z - mr); e.w = __expf(v.w - mr);
    ssum += (e.x + e.y) + (e.z + e.w);
    dot  += e.x * (v.x - mr) + e.y * (v.y - mr) + e.z * (v.z - mr) + e.w * (v.w - mr);
    raw[q] = e;
  }
  float inv = 1.f / ssum;
  float lns = __logf(ssum);
  #pragma unroll
  for (int q = 0; q < 16; ++q){
    float4 e = raw[q];
    raw[q] = make_float4(e.x * inv, e.y * inv, e.z * inv, e.w * inv);
  }
  float negent = dot * inv - lns;

  float oe = 0.f;
  const float* lvp = obs_lv + s * OBS_D;
  #pragma unroll
  for (int dd = 0; dd < OBS_D; dd += 4){
    float4 v = *(const float4*)(lvp + dd);
    oe += v.x + v.y + v.z + v.w;
  }
  oe += 0.5f * OBS_D * (1.f + LOG2PI);
  float R  = -negent + sumLnCp - oe;
  float Qc = R;
  __syncthreads();
  float Qa = hs[0] * R;

  for (int it = 1; it < H_DIM; ++it){
    Qlds[a][s] = Qc;
    __syncthreads();
    if (tid < 64){
      float m = -1e30f;
      #pragma unroll
      for (int aa = 0; aa < A_DIM; ++aa) m = fmaxf(m, Qlds[aa][lane]);
      float sv = 0.f;
      #pragma unroll
      for (int aa = 0; aa < A_DIM; ++aa) sv += __expf(Qlds[aa][lane] - m);
      Vs[lane] = m + __logf(sv);
    }
    __syncthreads();
    float hw = hs[it];
    float accA = 0.f, accB = 0.f;
    #pragma unroll
    for (int q = 0; q < 16; ++q){
      float4 v = *(const float4*)(&Vs[4 * q]);
      accA = fmaf(raw[q].x, v.x, fmaf(raw[q].y, v.y, accA));
      accB = fmaf(raw[q].z, v.z, fmaf(raw[q].w, v.w, accB));
    }
    Qc = R + accA + accB;
    Qa = fmaf(hw, Qc, Qa);
  }
  Qout[r] = Qa;
}

// ---------------- k_scan: time-chunked speculative scan, 8 chunks x 64 batch = 512 blocks ----------------
// Chunk c outputs t in [63c, min(500,63c+63)); c>0 burns in 8 steps from a uniform belief.
// Lane layout: so = lane&7 (s-octant), jj = lane>>3, j = 8*wave + jj.
__global__ __launch_bounds__(512, 4)
void k_scan(const _Float16* __restrict__ Bph,
            const float* __restrict__ lo,
            const float* __restrict__ pa,
            const float* __restrict__ Dlog,
            float* __restrict__ bseq){
  const int n   = blockIdx.x;
  const int c   = blockIdx.y;
  const int tid = threadIdx.x;
  const int g   = tid >> 6;
  const int l   = tid & 63;
  const int so  = l & 7;
  const int jj  = l >> 3;
  const int j   = g * 8 + jj;

  const int t_out0  = c * CHUNK_L;
  const int t_end   = (t_out0 + CHUNK_L < T_STEPS) ? (t_out0 + CHUNK_L) : T_STEPS;
  const int t_start = (c == 0) ? 0 : (t_out0 - BURN);
  const int nsteps  = t_end - t_start;   // 63 (c=0), 71 (1..6), 67 (c=7)

  __shared__ __align__(16) float lik_lds[MAXSTEPS][S_DIM];   // 18176 B
  __shared__ __align__(16) unsigned int b16[2][32];          // belief as f16 pairs
  __shared__ __align__(16) unsigned short ps16[2][8];        // per-wave partial sums, f16

  // ---- f16 Bp tile: Tq{A} = Bph[A][j][8so .. 8so+7]  (8 halves = uint4) ----
  #define DECLT(A) uint4 Tq##A;
  FOR16(DECLT)
  #define LOADT(A) Tq##A = *(const uint4*)(Bph + ((A) * 4096 + j * 64 + 8 * so));
  FOR16(LOADT)
  #define PINT(A) asm volatile("" : "+v"(Tq##A.x), "+v"(Tq##A.y), "+v"(Tq##A.z), "+v"(Tq##A.w));
  FOR16(PINT)

  // ---- prologue: stage lik rows [t_start, t_start+nsteps) into LDS (coalesced) ----
  const float* lo_n = lo + n * 64;     // + t*4096 + col
  const float* pa_n = pa + n * 16;     // + t*1024 + a (block-uniform -> scalar loads)
  for (int i = tid; i < nsteps * 64; i += 512){
    int r = i >> 6, col = i & 63;
    lik_lds[r][col] = lo_n[(t_start + r) * 4096 + col];
  }
  if (tid < 64){
    // chunk 0: true b0 = softmax(Dlog); others: uniform (softmax of zeros)
    float dl = (c == 0) ? Dlog[l] : 0.f;
    float m = wmax(dl);
    float e = __expf(dl - m);
    float s = wsum(e);
    float b0 = e / s;
    if (c == 0) bseq[n * 64 + l] = b0;
    float nb = __shfl_xor(b0, 1, 64);
    if (!(l & 1)) b16[0][l >> 1] = pack_pkrtz(b0, nb);
  }
  if (tid < 8) ps16[0][tid] = 0x3000;   // f16(0.125): 8 wave-partials sum to 1
  __syncthreads();

  for (int r = g; r < nsteps; r += 8){
    float v = lik_lds[r][l];
    float m = wmax(v);
    lik_lds[r][l] = __expf(v - m);
  }
  __syncthreads();

  // pa double-buffered scalar prefetch
  #define DECLPA(A) float pac_##A, pan_##A;
  FOR16(DECLPA)
  const float* pp0 = pa_n + t_start * 1024;
  #define LDPA0(A) pac_##A = pp0[A];
  FOR16(LDPA0)

  int cur = 0;
  for (int tt = 0; tt < nsteps; ++tt){
    const int t   = t_start + tt;
    const int nxt = cur ^ 1;

    // ---- prefetch pa[t+1] (scalar/SMEM; lands before BAR drain) ----
    const int t1 = (t + 1 < T_STEPS) ? (t + 1) : (T_STEPS - 1);
    const float* pp1 = pa_n + t1 * 1024;
    #define LDPAN(A) pan_##A = pp1[A];
    FOR16(LDPAN)

    // ---- per-step LDS reads ----
    float likr = lik_lds[tt][j];
    uint4 q = *(const uint4*)&ps16[cur][0];
    v2h a01 = u2h(q.x) + u2h(q.y);
    v2h a23 = u2h(q.z) + u2h(q.w);
    v2h aa  = a01 + a23;
    float sum = (float)aa.x + (float)aa.y;
    float lik = likr * __builtin_amdgcn_rcpf(sum);

    // ---- belief octant (8 f16 = one uint4, 8-way same-address broadcast) ----
    uint4 bq = *(const uint4*)&b16[cur][so * 4];
    v2h bh0 = u2h(bq.x), bh1 = u2h(bq.y), bh2 = u2h(bq.z), bh3 = u2h(bq.w);

    float pr0 = 0.f, pr1 = 0.f, pr2 = 0.f, pr3 = 0.f;
    #define DOTQ(A, P) { \
      float y = __builtin_amdgcn_fdot2(u2h(Tq##A.x), bh0, \
                __builtin_amdgcn_fdot2(u2h(Tq##A.y), bh1, \
                __builtin_amdgcn_fdot2(u2h(Tq##A.z), bh2, \
                __builtin_amdgcn_fdot2(u2h(Tq##A.w), bh3, 0.f, false), false), false), false); \
      P = fmaf(pac_##A, y, P); }
    DOTQ(0,  pr0) DOTQ(1,  pr1) DOTQ(2,  pr2) DOTQ(3,  pr3)
    DOTQ(4,  pr0) DOTQ(5,  pr1) DOTQ(6,  pr2) DOTQ(7,  pr3)
    DOTQ(8,  pr0) DOTQ(9,  pr1) DOTQ(10, pr2) DOTQ(11, pr3)
    DOTQ(12, pr0) DOTQ(13, pr1) DOTQ(14, pr2) DOTQ(15, pr3)
    float pri = (pr0 + pr1) + (pr2 + pr3);

    // butterfly over s-octants — all lanes get full prior[j]
    pri = dpp_add<0xB1>(pri);    // quad_perm xor1
    pri = dpp_add<0x4E>(pri);    // quad_perm xor2
    pri = dpp_add<0x141>(pri);   // row_half_mirror (xor7)

    float post = pri * lik;
    if (t >= t_out0){            // only own outputs (burn-in suppressed)
      if (so == 0)
        bseq[(t + 1) * 4096 + n * 64 + j] = post;   // fire-and-forget (vmcnt, survives BAR)
    }

    // pack (post_j, post_{j+1}) -> b16[nxt] from lanes l%16==0
    {
      int x = __builtin_amdgcn_update_dpp(0, __float_as_int(post), 0x128, 0xF, 0xF, true); // row_ror:8
      if (!(l & 15)) b16[nxt][g * 4 + (l >> 4)] = pack_pkrtz(post, __int_as_float(x));
    }

    // per-wave sum of post -> ps16[nxt] (f16; any block-uniform scale works — k_out renormalizes)
    {
      float w = post;
      w = dpp_add<0x128>(w);
      w = dpp_add<0x142>(w);
      w = dpp_add<0x143>(w);
      if (l == 48) ps16[nxt][g] = (unsigned short)(pack_pkrtz(w, 0.f) & 0xffffu);
    }

    // rotate pa
    #define CPPA(A) pac_##A = pan_##A;
    FOR16(CPPA)

    BAR();
    cur = nxt;
  }
}

// ---------------- epilogue: logp_pi + logp_obs, fully parallel over (t,n) ----------------
__global__ __launch_bounds__(256, 1) void k_out(const float* __restrict__ bseq,
                                                const float* __restrict__ Qg,
                                                const float* __restrict__ lo,
                                                const float* __restrict__ lu,
                                                float* __restrict__ out){
  __shared__ __align__(16) float Qs[A_DIM][S_DIM];
  const int tid = threadIdx.x;
  for (int i = tid; i < A_DIM * S_DIM; i += 256) Qs[i >> 6][i & 63] = Qg[i];
  __syncthreads();

  const int item = blockIdx.x * 256 + tid;   // t*64 + n
  float bs[64];
  const float* bp_ = bseq + item * 64;
  float bsum = 0.f;
  #pragma unroll
  for (int i = 0; i < 16; ++i){
    float4 v = *(const float4*)(bp_ + 4 * i);
    bs[4*i] = v.x; bs[4*i+1] = v.y; bs[4*i+2] = v.z; bs[4*i+3] = v.w;
    bsum += (v.x + v.y) + (v.z + v.w);
  }
  float binv = 1.0f / bsum;

  float G[A_DIM];
  #pragma unroll
  for (int a = 0; a < A_DIM; ++a){
    float acc = 0.f;
    #pragma unroll
    for (int s = 0; s < 64; ++s) acc = fmaf(bs[s], Qs[a][s], acc);
    G[a] = acc * binv;
  }
  const float* lup = lu + item * A_DIM;
  float m1 = -1e30f, m0 = -1e30f;
  float x1[A_DIM];
  #pragma unroll
  for (int a = 0; a < A_DIM; ++a){
    x1[a] = G[a] + lup[a];
    m1 = fmaxf(m1, x1[a]);
    m0 = fmaxf(m0, G[a]);
  }
  float e1 = 0.f, e0 = 0.f;
  #pragma unroll
  for (int a = 0; a < A_DIM; ++a){
    e1 += __expf(x1[a] - m1);
    e0 += __expf(G[a] - m0);
  }
  out[item] = (m1 + __logf(e1)) - (m0 + __logf(e0));

  // logp_obs: uses b[t+1] and lo[t]
  const float* bq = bseq + (item + 64) * 64;
  float bsum2 = 0.f;
  #pragma unroll
  for (int i = 0; i < 16; ++i){
    float4 v = *(const float4*)(bq + 4 * i);
    bs[4*i] = v.x; bs[4*i+1] = v.y; bs[4*i+2] = v.z; bs[4*i+3] = v.w;
    bsum2 += (v.x + v.y) + (v.z + v.w);
  }
  float inv2 = 1.0f / bsum2;
  const float* lop = lo + item * 64;
  float terms[64];
  float mt = -1e30f;
  #pragma unroll
  for (int i = 0; i < 16; ++i){
    float4 v = *(const float4*)(lop + 4 * i);
    float t0 = __logf(bs[4*i]   * inv2 + 1e-6f) * v.x;
    float t1 = __logf(bs[4*i+1] * inv2 + 1e-6f) * v.y;
    float t2 = __logf(bs[4*i+2] * inv2 + 1e-6f) * v.z;
    float t3 = __logf(bs[4*i+3] * inv2 + 1e-6f) * v.w;
    terms[4*i] = t0; terms[4*i+1] = t1; terms[4*i+2] = t2; terms[4*i+3] = t3;
    mt = fmaxf(mt, fmaxf(fmaxf(t0, t1), fmaxf(t2, t3)));
  }
  float es = 0.f;
  #pragma unroll
  for (int s = 0; s < 64; ++s) es += __expf(terms[s] - mt);
  out[T_STEPS * BATCH + item] = mt + __logf(es);
}

extern "C" void kernel_launch(void* const* d_in, const int* in_sizes, int n_in,
                              void* d_out, int out_size, void* d_ws, size_t ws_size,
                              hipStream_t stream){
  const float* o      = (const float*)d_in[0];
  const float* u      = (const float*)d_in[1];
  const float* obs_mu = (const float*)d_in[2];
  const float* obs_lv = (const float*)d_in[3];
  const float* obs_tl = (const float*)d_in[4];
  const float* ctl_mu = (const float*)d_in[5];
  const float* ctl_lv = (const float*)d_in[6];
  const float* ctl_tl = (const float*)d_in[7];
  const float* Blog   = (const float*)d_in[8];
  const float* Dlog   = (const float*)d_in[9];
  const float* Clog   = (const float*)d_in[10];
  const float* tau    = (const float*)d_in[11];
  float* out = (float*)d_out;
  float* ws  = (float*)d_ws;

  _Float16* Bph = (_Float16*)ws;       // 65536 halves = 32768 f32 slots ([a][j][s])
  float* Q    = ws + 32768;            // 1024
  float* lo   = ws + 33792;            // 2,048,000
  float* lu   = ws + 2081792;          // 512,000
  float* pa   = ws + 2593792;          // 512,000
  float* bseq = ws + 3105792;          // 501*4096 = 2,052,096   (total ~20.6 MiB)

  k_front<<<8381, 256, 0, stream>>>(o, obs_mu, obs_lv, obs_tl, Blog,
                                    u, ctl_mu, ctl_lv, ctl_tl, lo, Bph, lu, pa);
  k_vi   <<<1, 1024, 0, stream>>>(Blog, obs_lv, Clog, tau, Q);
  k_scan <<<dim3(64, CHUNKS), 512, 0, stream>>>(Bph, lo, pa, Dlog, bseq);
  k_out  <<<125, 256, 0, stream>>>(bseq, Q, lo, lu, out);
}

// Round 20
// 184.828 us; speedup vs baseline: 1.1544x; 1.0390x over previous
//
#include <hip/hip_runtime.h>
#include <math.h>

#define T_STEPS 500
#define BATCH   64
#define S_DIM   64
#define A_DIM   16
#define OBS_D   32
#define CTL_D   8
#define H_DIM   30

#define CHUNKS   8
#define CHUNK_L  63      // 8*63 = 504 >= 500
#define BURN     4
#define MAXSTEPS (CHUNK_L + BURN)   // 67

#define LOG2PI 1.8378770664093453f

typedef _Float16 v2h __attribute__((ext_vector_type(2)));
typedef __fp16  fp16x2 __attribute__((ext_vector_type(2)));

__device__ __forceinline__ float wmax(float v){
  #pragma unroll
  for (int o = 32; o > 0; o >>= 1) v = fmaxf(v, __shfl_xor(v, o, 64));
  return v;
}
__device__ __forceinline__ float wsum(float v){
  #pragma unroll
  for (int o = 32; o > 0; o >>= 1) v += __shfl_xor(v, o, 64);
  return v;
}

template<int CTRL>
__device__ __forceinline__ float dpp_add(float v){
  int x = __builtin_amdgcn_update_dpp(0, __float_as_int(v), CTRL, 0xF, 0xF, true);
  return v + __int_as_float(x);
}
__device__ __forceinline__ v2h u2h(unsigned int x){
  union { unsigned int u; v2h h; } c; c.u = x; return c.h;
}
__device__ __forceinline__ unsigned int pack_pkrtz(float a, float b){
  union { fp16x2 h; unsigned int u; } c;
  c.h = __builtin_amdgcn_cvt_pkrtz(a, b);
  return c.u;
}

// raw barrier: drain LDS/SMEM only — global loads/stores (vmcnt) stay in flight
#define BAR() do { \
  asm volatile("s_waitcnt lgkmcnt(0)" ::: "memory"); \
  __builtin_amdgcn_s_barrier(); \
  asm volatile("" ::: "memory"); \
  __builtin_amdgcn_sched_barrier(0); \
} while (0)

#define FOR16(X) X(0) X(1) X(2) X(3) X(4) X(5) X(6) X(7) X(8) X(9) X(10) X(11) X(12) X(13) X(14) X(15)

// ---------------- k_front: logp_o (bx<8000) + Bp^T f16 softmax (<8256) + logp_u/p_a (<8381) ----------------
__global__ __launch_bounds__(256) void k_front(const float* __restrict__ o,
                                               const float* __restrict__ obs_mu,
                                               const float* __restrict__ obs_lv,
                                               const float* __restrict__ obs_tl,
                                               const float* __restrict__ Blog,
                                               const float* __restrict__ u,
                                               const float* __restrict__ ctl_mu,
                                               const float* __restrict__ ctl_lv,
                                               const float* __restrict__ ctl_tl,
                                               float* __restrict__ lo_out,
                                               _Float16* __restrict__ Bph,
                                               float* __restrict__ lup,
                                               float* __restrict__ pap){
  const int bx  = blockIdx.x;
  const int tid = threadIdx.x;

  if (bx < 8000){
    const int k = bx & 63;
    const float* __restrict__ Lk  = obs_tl + k * OBS_D * OBS_D;
    const float* __restrict__ muk = obs_mu + k * OBS_D;
    const float* __restrict__ lvk = obs_lv + k * OBS_D;

    float dinv[OBS_D];
    float lvsum = 0.f;
    #pragma unroll
    for (int i = 0; i < OBS_D; ++i){
      float x = lvk[i];
      lvsum += x;
      dinv[i] = __expf(-x);
    }

    const int item = (bx >> 6) * 256 + tid;   // 125*256 = 32000
    const float* op = o + item * OBS_D;
    float d[OBS_D];
    #pragma unroll
    for (int i = 0; i < OBS_D; i += 4){
      float4 v = *(const float4*)(op + i);
      d[i]   = v.x - muk[i];
      d[i+1] = v.y - muk[i+1];
      d[i+2] = v.z - muk[i+2];
      d[i+3] = v.w - muk[i+3];
    }
    float z[OBS_D];
    float acc = 0.f;
    #pragma unroll
    for (int i = 0; i < OBS_D; ++i){
      float s0 = d[i], s1 = 0.f;
      #pragma unroll
      for (int jj = 0; jj + 1 < i; jj += 2){
        s0 = fmaf(-Lk[i * OBS_D + jj],     z[jj],     s0);
        s1 = fmaf(-Lk[i * OBS_D + jj + 1], z[jj + 1], s1);
      }
      if (i & 1) s0 = fmaf(-Lk[i * OBS_D + i - 1], z[i - 1], s0);
      float zz = (s0 + s1) * dinv[i];
      z[i] = zz;
      acc  = fmaf(zz, zz, acc);
    }
    lo_out[item * S_DIM + k] = -0.5f * acc - lvsum - 0.5f * OBS_D * LOG2PI;
    return;
  }

  if (bx < 8256){
    // ---- Bp softmax rows, stored TRANSPOSED f16: Bph[a][j][s] ----
    const int row  = (bx - 8000) * 4 + (tid >> 6);   // row = a*64 + s
    const int lane = tid & 63;                        // lane = j
    float v = Blog[row * 64 + lane];
    float m = wmax(v);
    float e = __expf(v - m);
    float s = wsum(e);
    const int a  = row >> 6;
    const int ss = row & 63;
    Bph[(a * 64 + lane) * 64 + ss] = (_Float16)(e / s);
    return;
  }

  // ---- logp_u + p_a ----
  const int item = (bx - 8256) * 256 + tid;   // 125*256 = 32000
  const float* up = u + item * CTL_D;
  float uu[CTL_D];
  #pragma unroll
  for (int i = 0; i < CTL_D; i += 4){
    float4 v = *(const float4*)(up + i);
    uu[i] = v.x; uu[i+1] = v.y; uu[i+2] = v.z; uu[i+3] = v.w;
  }
  float lp[A_DIM];
  #pragma unroll
  for (int a = 0; a < A_DIM; ++a){
    float z[CTL_D];
    float acc = 0.f, lvs = 0.f;
    #pragma unroll
    for (int i = 0; i < CTL_D; ++i){
      float lvv = ctl_lv[a * CTL_D + i];
      lvs += lvv;
      float s = uu[i] - ctl_mu[a * CTL_D + i];
      #pragma unroll
      for (int jj = 0; jj < i; ++jj) s = fmaf(-ctl_tl[a * 64 + i * CTL_D + jj], z[jj], s);
      z[i] = s * __expf(-lvv);
      acc  = fmaf(z[i], z[i], acc);
    }
    lp[a] = -0.5f * acc - lvs - 0.5f * CTL_D * LOG2PI;
  }
  float m = -1e30f;
  #pragma unroll
  for (int a = 0; a < A_DIM; ++a) m = fmaxf(m, lp[a]);
  float e[A_DIM], se = 0.f;
  #pragma unroll
  for (int a = 0; a < A_DIM; ++a){ e[a] = __expf(lp[a] - m); se += e[a]; }
  float inv = 1.f / se;
  #pragma unroll
  for (int a = 0; a < A_DIM; ++a){
    lup[item * A_DIM + a] = lp[a];
    pap[item * A_DIM + a] = e[a] * inv;
  }
}

// ---------------- k_vi: 1024 threads, 1 (a,s) row per thread ----------------
__global__ __launch_bounds__(1024, 1) void k_vi(const float* __restrict__ Blog,
                                                const float* __restrict__ obs_lv,
                                                const float* __restrict__ Clog,
                                                const float* __restrict__ tau,
                                                float* __restrict__ Qout){
  const int tid  = threadIdx.x;
  const int lane = tid & 63;
  __shared__ __align__(16) float Vs[S_DIM];
  __shared__ __align__(16) float Qlds[A_DIM][S_DIM];
  __shared__ float hs[H_DIM];

  float c  = Clog[lane];
  float cm = wmax(c);
  float cs = wsum(__expf(c - cm));
  float lseC = cm + __logf(cs);
  float sumLnCp = wsum(c) - 64.f * lseC;

  if (tid < 64){
    float t0   = tau[0];
    float rate = __expf(t0);
    float lg = 0.f;
    for (int i = 2; i <= lane; ++i) lg += __logf((float)i);
    float lh = (lane < H_DIM) ? ((float)lane * t0 - rate - lg) : -1e30f;
    float m  = wmax(lh);
    float e  = (lane < H_DIM) ? __expf(lh - m) : 0.f;
    float s  = wsum(e);
    if (lane < H_DIM) hs[lane] = e / s;
  }

  const int r = tid;               // a*64 + s
  const int a = r >> 6, s = r & 63;
  const float* p = Blog + r * 64;
  float4 raw[16];
  float mr = -1e30f;
  #pragma unroll
  for (int q = 0; q < 16; ++q){
    float4 v = *(const float4*)(p + 4 * q);
    raw[q] = v;
    mr = fmaxf(mr, fmaxf(fmaxf(v.x, v.y), fmaxf(v.z, v.w)));
  }
  float ssum = 0.f, dot = 0.f;
  #pragma unroll
  for (int q = 0; q < 16; ++q){
    float4 v = raw[q];
    float4 e;
    e.x = __expf(v.x - mr); e.y = __expf(v.y - mr);
    e.z = __expf(v.z - mr); e.w = __expf(v.w - mr);
    ssum += (e.x + e.y) + (e.z + e.w);
    dot  += e.x * (v.x - mr) + e.y * (v.y - mr) + e.z * (v.z - mr) + e.w * (v.w - mr);
    raw[q] = e;
  }
  float inv = 1.f / ssum;
  float lns = __logf(ssum);
  #pragma unroll
  for (int q = 0; q < 16; ++q){
    float4 e = raw[q];
    raw[q] = make_float4(e.x * inv, e.y * inv, e.z * inv, e.w * inv);
  }
  float negent = dot * inv - lns;

  float oe = 0.f;
  const float* lvp = obs_lv + s * OBS_D;
  #pragma unroll
  for (int dd = 0; dd < OBS_D; dd += 4){
    float4 v = *(const float4*)(lvp + dd);
    oe += v.x + v.y + v.z + v.w;
  }
  oe += 0.5f * OBS_D * (1.f + LOG2PI);
  float R  = -negent + sumLnCp - oe;
  float Qc = R;
  __syncthreads();
  float Qa = hs[0] * R;

  for (int it = 1; it < H_DIM; ++it){
    Qlds[a][s] = Qc;
    __syncthreads();
    if (tid < 64){
      float m = -1e30f;
      #pragma unroll
      for (int aa = 0; aa < A_DIM; ++aa) m = fmaxf(m, Qlds[aa][lane]);
      float sv = 0.f;
      #pragma unroll
      for (int aa = 0; aa < A_DIM; ++aa) sv += __expf(Qlds[aa][lane] - m);
      Vs[lane] = m + __logf(sv);
    }
    __syncthreads();
    float hw = hs[it];
    float accA = 0.f, accB = 0.f;
    #pragma unroll
    for (int q = 0; q < 16; ++q){
      float4 v = *(const float4*)(&Vs[4 * q]);
      accA = fmaf(raw[q].x, v.x, fmaf(raw[q].y, v.y, accA));
      accB = fmaf(raw[q].z, v.z, fmaf(raw[q].w, v.w, accB));
    }
    Qc = R + accA + accB;
    Qa = fmaf(hw, Qc, Qa);
  }
  Qout[r] = Qa;
}

// ---------------- k_scan: time-chunked speculative scan, 8 chunks x 64 batch = 512 blocks ----------------
// Chunk c outputs t in [63c, min(500,63c+63)); c>0 burns in 4 steps from a uniform belief.
// Lane layout: so = lane&7 (s-octant), jj = lane>>3, j = 8*wave + jj.
__global__ __launch_bounds__(512, 4)
void k_scan(const _Float16* __restrict__ Bph,
            const float* __restrict__ lo,
            const float* __restrict__ pa,
            const float* __restrict__ Dlog,
            float* __restrict__ bseq){
  const int n   = blockIdx.x;
  const int c   = blockIdx.y;
  const int tid = threadIdx.x;
  const int g   = tid >> 6;
  const int l   = tid & 63;
  const int so  = l & 7;
  const int jj  = l >> 3;
  const int j   = g * 8 + jj;

  const int t_out0  = c * CHUNK_L;
  const int t_end   = (t_out0 + CHUNK_L < T_STEPS) ? (t_out0 + CHUNK_L) : T_STEPS;
  const int t_start = (c == 0) ? 0 : (t_out0 - BURN);
  const int nsteps  = t_end - t_start;   // 63 (c=0), 67 (1..6), 63 (c=7)

  __shared__ __align__(16) float lik_lds[MAXSTEPS][S_DIM];   // 17152 B
  __shared__ __align__(16) unsigned int b16[2][32];          // belief as f16 pairs
  __shared__ __align__(16) unsigned short ps16[2][8];        // per-wave partial sums, f16

  // ---- f16 Bp tile: Tq{A} = Bph[A][j][8so .. 8so+7]  (8 halves = uint4) ----
  #define DECLT(A) uint4 Tq##A;
  FOR16(DECLT)
  #define LOADT(A) Tq##A = *(const uint4*)(Bph + ((A) * 4096 + j * 64 + 8 * so));
  FOR16(LOADT)
  #define PINT(A) asm volatile("" : "+v"(Tq##A.x), "+v"(Tq##A.y), "+v"(Tq##A.z), "+v"(Tq##A.w));
  FOR16(PINT)

  // ---- prologue: stage lik rows [t_start, t_start+nsteps) into LDS (coalesced) ----
  const float* lo_n = lo + n * 64;     // + t*4096 + col
  const float* pa_n = pa + n * 16;     // + t*1024 + a (block-uniform -> scalar loads)
  for (int i = tid; i < nsteps * 64; i += 512){
    int r = i >> 6, col = i & 63;
    lik_lds[r][col] = lo_n[(t_start + r) * 4096 + col];
  }
  if (tid < 64){
    // chunk 0: true b0 = softmax(Dlog); others: uniform (softmax of zeros)
    float dl = (c == 0) ? Dlog[l] : 0.f;
    float m = wmax(dl);
    float e = __expf(dl - m);
    float s = wsum(e);
    float b0 = e / s;
    if (c == 0) bseq[n * 64 + l] = b0;
    float nb = __shfl_xor(b0, 1, 64);
    if (!(l & 1)) b16[0][l >> 1] = pack_pkrtz(b0, nb);
  }
  if (tid < 8) ps16[0][tid] = 0x3000;   // f16(0.125): 8 wave-partials sum to 1
  __syncthreads();

  for (int r = g; r < nsteps; r += 8){
    float v = lik_lds[r][l];
    float m = wmax(v);
    lik_lds[r][l] = __expf(v - m);
  }
  __syncthreads();

  // pa double-buffered scalar prefetch
  #define DECLPA(A) float pac_##A, pan_##A;
  FOR16(DECLPA)
  const float* pp0 = pa_n + t_start * 1024;
  #define LDPA0(A) pac_##A = pp0[A];
  FOR16(LDPA0)

  int cur = 0;
  for (int tt = 0; tt < nsteps; ++tt){
    const int t   = t_start + tt;
    const int nxt = cur ^ 1;

    // ---- prefetch pa[t+1] (scalar/SMEM; lands before BAR drain) ----
    const int t1 = (t + 1 < T_STEPS) ? (t + 1) : (T_STEPS - 1);
    const float* pp1 = pa_n + t1 * 1024;
    #define LDPAN(A) pan_##A = pp1[A];
    FOR16(LDPAN)

    // ---- per-step LDS reads ----
    float likr = lik_lds[tt][j];
    uint4 q = *(const uint4*)&ps16[cur][0];
    v2h a01 = u2h(q.x) + u2h(q.y);
    v2h a23 = u2h(q.z) + u2h(q.w);
    v2h aa  = a01 + a23;
    float sum = (float)aa.x + (float)aa.y;
    float lik = likr * __builtin_amdgcn_rcpf(sum);

    // ---- belief octant (8 f16 = one uint4, 8-way same-address broadcast) ----
    uint4 bq = *(const uint4*)&b16[cur][so * 4];
    v2h bh0 = u2h(bq.x), bh1 = u2h(bq.y), bh2 = u2h(bq.z), bh3 = u2h(bq.w);

    float pr0 = 0.f, pr1 = 0.f, pr2 = 0.f, pr3 = 0.f;
    #define DOTQ(A, P) { \
      float y = __builtin_amdgcn_fdot2(u2h(Tq##A.x), bh0, \
                __builtin_amdgcn_fdot2(u2h(Tq##A.y), bh1, \
                __builtin_amdgcn_fdot2(u2h(Tq##A.z), bh2, \
                __builtin_amdgcn_fdot2(u2h(Tq##A.w), bh3, 0.f, false), false), false), false); \
      P = fmaf(pac_##A, y, P); }
    DOTQ(0,  pr0) DOTQ(1,  pr1) DOTQ(2,  pr2) DOTQ(3,  pr3)
    DOTQ(4,  pr0) DOTQ(5,  pr1) DOTQ(6,  pr2) DOTQ(7,  pr3)
    DOTQ(8,  pr0) DOTQ(9,  pr1) DOTQ(10, pr2) DOTQ(11, pr3)
    DOTQ(12, pr0) DOTQ(13, pr1) DOTQ(14, pr2) DOTQ(15, pr3)
    float pri = (pr0 + pr1) + (pr2 + pr3);

    // butterfly over s-octants — all lanes get full prior[j]
    pri = dpp_add<0xB1>(pri);    // quad_perm xor1
    pri = dpp_add<0x4E>(pri);    // quad_perm xor2
    pri = dpp_add<0x141>(pri);   // row_half_mirror (xor7)

    float post = pri * lik;
    if (t >= t_out0){            // only own outputs (burn-in suppressed)
      if (so == 0)
        bseq[(t + 1) * 4096 + n * 64 + j] = post;   // fire-and-forget (vmcnt, survives BAR)
    }

    // pack (post_j, post_{j+1}) -> b16[nxt] from lanes l%16==0
    {
      int x = __builtin_amdgcn_update_dpp(0, __float_as_int(post), 0x128, 0xF, 0xF, true); // row_ror:8
      if (!(l & 15)) b16[nxt][g * 4 + (l >> 4)] = pack_pkrtz(post, __int_as_float(x));
    }

    // per-wave sum of post -> ps16[nxt] (f16; any block-uniform scale works — k_out renormalizes)
    {
      float w = post;
      w = dpp_add<0x128>(w);
      w = dpp_add<0x142>(w);
      w = dpp_add<0x143>(w);
      if (l == 48) ps16[nxt][g] = (unsigned short)(pack_pkrtz(w, 0.f) & 0xffffu);
    }

    // rotate pa
    #define CPPA(A) pac_##A = pan_##A;
    FOR16(CPPA)

    BAR();
    cur = nxt;
  }
}

// ---------------- epilogue: logp_pi + logp_obs, fully parallel over (t,n) ----------------
__global__ __launch_bounds__(128, 1) void k_out(const float* __restrict__ bseq,
                                                const float* __restrict__ Qg,
                                                const float* __restrict__ lo,
                                                const float* __restrict__ lu,
                                                float* __restrict__ out){
  __shared__ __align__(16) float Qs[A_DIM][S_DIM];
  const int tid = threadIdx.x;
  for (int i = tid; i < A_DIM * S_DIM; i += 128) Qs[i >> 6][i & 63] = Qg[i];
  __syncthreads();

  const int item = blockIdx.x * 128 + tid;   // t*64 + n
  float bs[64];
  const float* bp_ = bseq + item * 64;
  float bsum = 0.f;
  #pragma unroll
  for (int i = 0; i < 16; ++i){
    float4 v = *(const float4*)(bp_ + 4 * i);
    bs[4*i] = v.x; bs[4*i+1] = v.y; bs[4*i+2] = v.z; bs[4*i+3] = v.w;
    bsum += (v.x + v.y) + (v.z + v.w);
  }
  float binv = 1.0f / bsum;

  float G[A_DIM];
  #pragma unroll
  for (int a = 0; a < A_DIM; ++a){
    float acc = 0.f;
    #pragma unroll
    for (int s = 0; s < 64; ++s) acc = fmaf(bs[s], Qs[a][s], acc);
    G[a] = acc * binv;
  }
  const float* lup = lu + item * A_DIM;
  float m1 = -1e30f, m0 = -1e30f;
  float x1[A_DIM];
  #pragma unroll
  for (int a = 0; a < A_DIM; ++a){
    x1[a] = G[a] + lup[a];
    m1 = fmaxf(m1, x1[a]);
    m0 = fmaxf(m0, G[a]);
  }
  float e1 = 0.f, e0 = 0.f;
  #pragma unroll
  for (int a = 0; a < A_DIM; ++a){
    e1 += __expf(x1[a] - m1);
    e0 += __expf(G[a] - m0);
  }
  out[item] = (m1 + __logf(e1)) - (m0 + __logf(e0));

  // logp_obs: uses b[t+1] and lo[t]
  const float* bq = bseq + (item + 64) * 64;
  float bsum2 = 0.f;
  #pragma unroll
  for (int i = 0; i < 16; ++i){
    float4 v = *(const float4*)(bq + 4 * i);
    bs[4*i] = v.x; bs[4*i+1] = v.y; bs[4*i+2] = v.z; bs[4*i+3] = v.w;
    bsum2 += (v.x + v.y) + (v.z + v.w);
  }
  float inv2 = 1.0f / bsum2;
  const float* lop = lo + item * 64;
  float terms[64];
  float mt = -1e30f;
  #pragma unroll
  for (int i = 0; i < 16; ++i){
    float4 v = *(const float4*)(lop + 4 * i);
    float t0 = __logf(bs[4*i]   * inv2 + 1e-6f) * v.x;
    float t1 = __logf(bs[4*i+1] * inv2 + 1e-6f) * v.y;
    float t2 = __logf(bs[4*i+2] * inv2 + 1e-6f) * v.z;
    float t3 = __logf(bs[4*i+3] * inv2 + 1e-6f) * v.w;
    terms[4*i] = t0; terms[4*i+1] = t1; terms[4*i+2] = t2; terms[4*i+3] = t3;
    mt = fmaxf(mt, fmaxf(fmaxf(t0, t1), fmaxf(t2, t3)));
  }
  float es = 0.f;
  #pragma unroll
  for (int s = 0; s < 64; ++s) es += __expf(terms[s] - mt);
  out[T_STEPS * BATCH + item] = mt + __logf(es);
}

extern "C" void kernel_launch(void* const* d_in, const int* in_sizes, int n_in,
                              void* d_out, int out_size, void* d_ws, size_t ws_size,
                              hipStream_t stream){
  const float* o      = (const float*)d_in[0];
  const float* u      = (const float*)d_in[1];
  const float* obs_mu = (const float*)d_in[2];
  const float* obs_lv = (const float*)d_in[3];
  const float* obs_tl = (const float*)d_in[4];
  const float* ctl_mu = (const float*)d_in[5];
  const float* ctl_lv = (const float*)d_in[6];
  const float* ctl_tl = (const float*)d_in[7];
  const float* Blog   = (const float*)d_in[8];
  const float* Dlog   = (const float*)d_in[9];
  const float* Clog   = (const float*)d_in[10];
  const float* tau    = (const float*)d_in[11];
  float* out = (float*)d_out;
  float* ws  = (float*)d_ws;

  _Float16* Bph = (_Float16*)ws;       // 65536 halves = 32768 f32 slots ([a][j][s])
  float* Q    = ws + 32768;            // 1024
  float* lo   = ws + 33792;            // 2,048,000
  float* lu   = ws + 2081792;          // 512,000
  float* pa   = ws + 2593792;          // 512,000
  float* bseq = ws + 3105792;          // 501*4096 = 2,052,096   (total ~20.6 MiB)

  k_front<<<8381, 256, 0, stream>>>(o, obs_mu, obs_lv, obs_tl, Blog,
                                    u, ctl_mu, ctl_lv, ctl_tl, lo, Bph, lu, pa);
  k_vi   <<<1, 1024, 0, stream>>>(Blog, obs_lv, Clog, tau, Q);
  k_scan <<<dim3(64, CHUNKS), 512, 0, stream>>>(Bph, lo, pa, Dlog, bseq);
  k_out  <<<250, 128, 0, stream>>>(bseq, Q, lo, lu, out);
}

// Round 21
// 169.783 us; speedup vs baseline: 1.2567x; 1.0886x over previous
//
#include <hip/hip_runtime.h>
#include <math.h>

#define T_STEPS 500
#define BATCH   64
#define S_DIM   64
#define A_DIM   16
#define OBS_D   32
#define CTL_D   8
#define H_DIM   30

#define CHUNKS   8
#define CHUNK_L  63      // 8*63 = 504 >= 500
#define BURN     2
#define MAXSTEPS (CHUNK_L + BURN)   // 65

#define LOG2PI 1.8378770664093453f

typedef _Float16 v2h __attribute__((ext_vector_type(2)));
typedef __fp16  fp16x2 __attribute__((ext_vector_type(2)));

__device__ __forceinline__ float wmax(float v){
  #pragma unroll
  for (int o = 32; o > 0; o >>= 1) v = fmaxf(v, __shfl_xor(v, o, 64));
  return v;
}
__device__ __forceinline__ float wsum(float v){
  #pragma unroll
  for (int o = 32; o > 0; o >>= 1) v += __shfl_xor(v, o, 64);
  return v;
}

template<int CTRL>
__device__ __forceinline__ float dpp_add(float v){
  int x = __builtin_amdgcn_update_dpp(0, __float_as_int(v), CTRL, 0xF, 0xF, true);
  return v + __int_as_float(x);
}
__device__ __forceinline__ v2h u2h(unsigned int x){
  union { unsigned int u; v2h h; } c; c.u = x; return c.h;
}
__device__ __forceinline__ unsigned int pack_pkrtz(float a, float b){
  union { fp16x2 h; unsigned int u; } c;
  c.h = __builtin_amdgcn_cvt_pkrtz(a, b);
  return c.u;
}

// raw barrier: drain LDS/SMEM only — global loads/stores (vmcnt) stay in flight
#define BAR() do { \
  asm volatile("s_waitcnt lgkmcnt(0)" ::: "memory"); \
  __builtin_amdgcn_s_barrier(); \
  asm volatile("" ::: "memory"); \
  __builtin_amdgcn_sched_barrier(0); \
} while (0)

#define FOR16(X) X(0) X(1) X(2) X(3) X(4) X(5) X(6) X(7) X(8) X(9) X(10) X(11) X(12) X(13) X(14) X(15)

// ---------------- k_front (1024 threads/block, grid 2145):
//   bx == 0           : VI  (independent of other outputs; dispatched first, hides under logp_o)
//   bx in [1, 2048]   : logp_o  (k = (bx-1)&63, chunk = (bx-1)>>6, 1000 items/block)
//   bx in [2049, 2112]: Bp softmax rows -> Bph f16 transposed ([a][j][s]), 16 rows/block
//   bx in [2113, 2144]: logp_u + p_a, 1000 items/block
__global__ __launch_bounds__(1024) void k_front(const float* __restrict__ o,
                                                const float* __restrict__ obs_mu,
                                                const float* __restrict__ obs_lv,
                                                const float* __restrict__ obs_tl,
                                                const float* __restrict__ Blog,
                                                const float* __restrict__ u,
                                                const float* __restrict__ ctl_mu,
                                                const float* __restrict__ ctl_lv,
                                                const float* __restrict__ ctl_tl,
                                                const float* __restrict__ Clog,
                                                const float* __restrict__ tau,
                                                float* __restrict__ lo_out,
                                                _Float16* __restrict__ Bph,
                                                float* __restrict__ lup,
                                                float* __restrict__ pap,
                                                float* __restrict__ Qout){
  const int bx  = blockIdx.x;
  const int tid = threadIdx.x;

  if (bx == 0){
    // ---- VI: 1024 threads, 1 (a,s) row per thread (f32, verbatim) ----
    const int lane = tid & 63;
    __shared__ __align__(16) float Vs[S_DIM];
    __shared__ __align__(16) float Qlds[A_DIM][S_DIM];
    __shared__ float hs[H_DIM];

    float c  = Clog[lane];
    float cm = wmax(c);
    float cs = wsum(__expf(c - cm));
    float lseC = cm + __logf(cs);
    float sumLnCp = wsum(c) - 64.f * lseC;

    if (tid < 64){
      float t0   = tau[0];
      float rate = __expf(t0);
      float lg = 0.f;
      for (int i = 2; i <= lane; ++i) lg += __logf((float)i);
      float lh = (lane < H_DIM) ? ((float)lane * t0 - rate - lg) : -1e30f;
      float m  = wmax(lh);
      float e  = (lane < H_DIM) ? __expf(lh - m) : 0.f;
      float s  = wsum(e);
      if (lane < H_DIM) hs[lane] = e / s;
    }

    const int r = tid;               // a*64 + s
    const int a = r >> 6, s = r & 63;
    const float* p = Blog + r * 64;
    float4 raw[16];
    float mr = -1e30f;
    #pragma unroll
    for (int q = 0; q < 16; ++q){
      float4 v = *(const float4*)(p + 4 * q);
      raw[q] = v;
      mr = fmaxf(mr, fmaxf(fmaxf(v.x, v.y), fmaxf(v.z, v.w)));
    }
    float ssum = 0.f, dot = 0.f;
    #pragma unroll
    for (int q = 0; q < 16; ++q){
      float4 v = raw[q];
      float4 e;
      e.x = __expf(v.x - mr); e.y = __expf(v.y - mr);
      e.z = __expf(v.z - mr); e.w = __expf(v.w - mr);
      ssum += (e.x + e.y) + (e.z + e.w);
      dot  += e.x * (v.x - mr) + e.y * (v.y - mr) + e.z * (v.z - mr) + e.w * (v.w - mr);
      raw[q] = e;
    }
    float inv = 1.f / ssum;
    float lns = __logf(ssum);
    #pragma unroll
    for (int q = 0; q < 16; ++q){
      float4 e = raw[q];
      raw[q] = make_float4(e.x * inv, e.y * inv, e.z * inv, e.w * inv);
    }
    float negent = dot * inv - lns;

    float oe = 0.f;
    const float* lvp = obs_lv + s * OBS_D;
    #pragma unroll
    for (int dd = 0; dd < OBS_D; dd += 4){
      float4 v = *(const float4*)(lvp + dd);
      oe += v.x + v.y + v.z + v.w;
    }
    oe += 0.5f * OBS_D * (1.f + LOG2PI);
    float R  = -negent + sumLnCp - oe;
    float Qc = R;
    __syncthreads();
    float Qa = hs[0] * R;

    for (int it = 1; it < H_DIM; ++it){
      Qlds[a][s] = Qc;
      __syncthreads();
      if (tid < 64){
        float m = -1e30f;
        #pragma unroll
        for (int aa = 0; aa < A_DIM; ++aa) m = fmaxf(m, Qlds[aa][lane]);
        float sv = 0.f;
        #pragma unroll
        for (int aa = 0; aa < A_DIM; ++aa) sv += __expf(Qlds[aa][lane] - m);
        Vs[lane] = m + __logf(sv);
      }
      __syncthreads();
      float hw = hs[it];
      float accA = 0.f, accB = 0.f;
      #pragma unroll
      for (int q = 0; q < 16; ++q){
        float4 v = *(const float4*)(&Vs[4 * q]);
        accA = fmaf(raw[q].x, v.x, fmaf(raw[q].y, v.y, accA));
        accB = fmaf(raw[q].z, v.z, fmaf(raw[q].w, v.w, accB));
      }
      Qc = R + accA + accB;
      Qa = fmaf(hw, Qc, Qa);
    }
    Qout[r] = Qa;
    return;
  }

  if (bx <= 2048){
    // ---- logp_o ----
    const int b2 = bx - 1;
    const int k  = b2 & 63;
    const float* __restrict__ Lk  = obs_tl + k * OBS_D * OBS_D;
    const float* __restrict__ muk = obs_mu + k * OBS_D;
    const float* __restrict__ lvk = obs_lv + k * OBS_D;

    float lvsum = 0.f;
    #pragma unroll
    for (int i = 0; i < OBS_D; ++i) lvsum += lvk[i];

    if (tid < 1000){
      const int item = (b2 >> 6) * 1000 + tid;   // 32 chunks * 1000 = 32000
      const float* op = o + item * OBS_D;
      float d[OBS_D];
      #pragma unroll
      for (int i = 0; i < OBS_D; i += 4){
        float4 v = *(const float4*)(op + i);
        d[i]   = v.x - muk[i];
        d[i+1] = v.y - muk[i+1];
        d[i+2] = v.z - muk[i+2];
        d[i+3] = v.w - muk[i+3];
      }
      float z[OBS_D];
      float acc = 0.f;
      #pragma unroll
      for (int i = 0; i < OBS_D; ++i){
        float s0 = d[i], s1 = 0.f;
        #pragma unroll
        for (int jj = 0; jj + 1 < i; jj += 2){
          s0 = fmaf(-Lk[i * OBS_D + jj],     z[jj],     s0);
          s1 = fmaf(-Lk[i * OBS_D + jj + 1], z[jj + 1], s1);
        }
        if (i & 1) s0 = fmaf(-Lk[i * OBS_D + i - 1], z[i - 1], s0);
        float zz = (s0 + s1) * __expf(-lvk[i]);
        z[i] = zz;
        acc  = fmaf(zz, zz, acc);
      }
      lo_out[item * S_DIM + k] = -0.5f * acc - lvsum - 0.5f * OBS_D * LOG2PI;
    }
    return;
  }

  if (bx <= 2112){
    // ---- Bp softmax rows, stored TRANSPOSED f16: Bph[a][j][s] ----
    const int row  = (bx - 2049) * 16 + (tid >> 6);  // 64 blocks * 16 rows = 1024
    const int lane = tid & 63;                        // lane = j
    float v = Blog[row * 64 + lane];
    float m = wmax(v);
    float e = __expf(v - m);
    float s = wsum(e);
    const int a  = row >> 6;
    const int ss = row & 63;
    Bph[(a * 64 + lane) * 64 + ss] = (_Float16)(e / s);
    return;
  }

  // ---- logp_u + p_a ----
  if (tid < 1000){
    const int item = (bx - 2113) * 1000 + tid;   // 32 * 1000 = 32000
    const float* up = u + item * CTL_D;
    float uu[CTL_D];
    #pragma unroll
    for (int i = 0; i < CTL_D; i += 4){
      float4 v = *(const float4*)(up + i);
      uu[i] = v.x; uu[i+1] = v.y; uu[i+2] = v.z; uu[i+3] = v.w;
    }
    float lp[A_DIM];
    #pragma unroll
    for (int a = 0; a < A_DIM; ++a){
      float z[CTL_D];
      float acc = 0.f, lvs = 0.f;
      #pragma unroll
      for (int i = 0; i < CTL_D; ++i){
        float lvv = ctl_lv[a * CTL_D + i];
        lvs += lvv;
        float s = uu[i] - ctl_mu[a * CTL_D + i];
        #pragma unroll
        for (int jj = 0; jj < i; ++jj) s = fmaf(-ctl_tl[a * 64 + i * CTL_D + jj], z[jj], s);
        z[i] = s * __expf(-lvv);
        acc  = fmaf(z[i], z[i], acc);
      }
      lp[a] = -0.5f * acc - lvs - 0.5f * CTL_D * LOG2PI;
    }
    float m = -1e30f;
    #pragma unroll
    for (int a = 0; a < A_DIM; ++a) m = fmaxf(m, lp[a]);
    float e[A_DIM], se = 0.f;
    #pragma unroll
    for (int a = 0; a < A_DIM; ++a){ e[a] = __expf(lp[a] - m); se += e[a]; }
    float inv = 1.f / se;
    #pragma unroll
    for (int a = 0; a < A_DIM; ++a){
      lup[item * A_DIM + a] = lp[a];
      pap[item * A_DIM + a] = e[a] * inv;
    }
  }
}

// ---------------- k_scan: time-chunked speculative scan, 8 chunks x 64 batch = 512 blocks ----------------
// Chunk c outputs t in [63c, min(500,63c+63)); c>0 burns in 2 steps from a uniform belief.
// Lane layout: so = lane&7 (s-octant), jj = lane>>3, j = 8*wave + jj.
__global__ __launch_bounds__(512, 4)
void k_scan(const _Float16* __restrict__ Bph,
            const float* __restrict__ lo,
            const float* __restrict__ pa,
            const float* __restrict__ Dlog,
            float* __restrict__ bseq){
  const int n   = blockIdx.x;
  const int c   = blockIdx.y;
  const int tid = threadIdx.x;
  const int g   = tid >> 6;
  const int l   = tid & 63;
  const int so  = l & 7;
  const int jj  = l >> 3;
  const int j   = g * 8 + jj;

  const int t_out0  = c * CHUNK_L;
  const int t_end   = (t_out0 + CHUNK_L < T_STEPS) ? (t_out0 + CHUNK_L) : T_STEPS;
  const int t_start = (c == 0) ? 0 : (t_out0 - BURN);
  const int nsteps  = t_end - t_start;

  __shared__ __align__(16) float lik_lds[MAXSTEPS][S_DIM];   // 16640 B
  __shared__ __align__(16) unsigned int b16[2][32];          // belief as f16 pairs
  __shared__ __align__(16) unsigned short ps16[2][8];        // per-wave partial sums, f16

  // ---- f16 Bp tile: Tq{A} = Bph[A][j][8so .. 8so+7]  (8 halves = uint4) ----
  #define DECLT(A) uint4 Tq##A;
  FOR16(DECLT)
  #define LOADT(A) Tq##A = *(const uint4*)(Bph + ((A) * 4096 + j * 64 + 8 * so));
  FOR16(LOADT)
  #define PINT(A) asm volatile("" : "+v"(Tq##A.x), "+v"(Tq##A.y), "+v"(Tq##A.z), "+v"(Tq##A.w));
  FOR16(PINT)

  // ---- prologue: stage lik rows [t_start, t_start+nsteps) into LDS (coalesced) ----
  const float* lo_n = lo + n * 64;     // + t*4096 + col
  const float* pa_n = pa + n * 16;     // + t*1024 + a (block-uniform -> scalar loads)
  for (int i = tid; i < nsteps * 64; i += 512){
    int r = i >> 6, col = i & 63;
    lik_lds[r][col] = lo_n[(t_start + r) * 4096 + col];
  }
  if (tid < 64){
    // chunk 0: true b0 = softmax(Dlog); others: uniform (softmax of zeros)
    float dl = (c == 0) ? Dlog[l] : 0.f;
    float m = wmax(dl);
    float e = __expf(dl - m);
    float s = wsum(e);
    float b0 = e / s;
    if (c == 0) bseq[n * 64 + l] = b0;
    float nb = __shfl_xor(b0, 1, 64);
    if (!(l & 1)) b16[0][l >> 1] = pack_pkrtz(b0, nb);
  }
  if (tid < 8) ps16[0][tid] = 0x3000;   // f16(0.125): 8 wave-partials sum to 1
  __syncthreads();

  for (int r = g; r < nsteps; r += 8){
    float v = lik_lds[r][l];
    float m = wmax(v);
    lik_lds[r][l] = __expf(v - m);
  }
  __syncthreads();

  // pa double-buffered scalar prefetch
  #define DECLPA(A) float pac_##A, pan_##A;
  FOR16(DECLPA)
  const float* pp0 = pa_n + t_start * 1024;
  #define LDPA0(A) pac_##A = pp0[A];
  FOR16(LDPA0)

  int cur = 0;
  for (int tt = 0; tt < nsteps; ++tt){
    const int t   = t_start + tt;
    const int nxt = cur ^ 1;

    // ---- prefetch pa[t+1] (scalar/SMEM; lands before BAR drain) ----
    const int t1 = (t + 1 < T_STEPS) ? (t + 1) : (T_STEPS - 1);
    const float* pp1 = pa_n + t1 * 1024;
    #define LDPAN(A) pan_##A = pp1[A];
    FOR16(LDPAN)

    // ---- per-step LDS reads ----
    float likr = lik_lds[tt][j];
    uint4 q = *(const uint4*)&ps16[cur][0];
    v2h a01 = u2h(q.x) + u2h(q.y);
    v2h a23 = u2h(q.z) + u2h(q.w);
    v2h aa  = a01 + a23;
    float sum = (float)aa.x + (float)aa.y;
    float lik = likr * __builtin_amdgcn_rcpf(sum);

    // ---- belief octant (8 f16 = one uint4, 8-way same-address broadcast) ----
    uint4 bq = *(const uint4*)&b16[cur][so * 4];
    v2h bh0 = u2h(bq.x), bh1 = u2h(bq.y), bh2 = u2h(bq.z), bh3 = u2h(bq.w);

    float pr0 = 0.f, pr1 = 0.f, pr2 = 0.f, pr3 = 0.f;
    #define DOTQ(A, P) { \
      float y = __builtin_amdgcn_fdot2(u2h(Tq##A.x), bh0, \
                __builtin_amdgcn_fdot2(u2h(Tq##A.y), bh1, \
                __builtin_amdgcn_fdot2(u2h(Tq##A.z), bh2, \
                __builtin_amdgcn_fdot2(u2h(Tq##A.w), bh3, 0.f, false), false), false), false); \
      P = fmaf(pac_##A, y, P); }
    DOTQ(0,  pr0) DOTQ(1,  pr1) DOTQ(2,  pr2) DOTQ(3,  pr3)
    DOTQ(4,  pr0) DOTQ(5,  pr1) DOTQ(6,  pr2) DOTQ(7,  pr3)
    DOTQ(8,  pr0) DOTQ(9,  pr1) DOTQ(10, pr2) DOTQ(11, pr3)
    DOTQ(12, pr0) DOTQ(13, pr1) DOTQ(14, pr2) DOTQ(15, pr3)
    float pri = (pr0 + pr1) + (pr2 + pr3);

    // butterfly over s-octants — all lanes get full prior[j]
    pri = dpp_add<0xB1>(pri);    // quad_perm xor1
    pri = dpp_add<0x4E>(pri);    // quad_perm xor2
    pri = dpp_add<0x141>(pri);   // row_half_mirror (xor7)

    float post = pri * lik;
    if (t >= t_out0){            // only own outputs (burn-in suppressed)
      if (so == 0)
        bseq[(t + 1) * 4096 + n * 64 + j] = post;   // fire-and-forget (vmcnt, survives BAR)
    }

    // pack (post_j, post_{j+1}) -> b16[nxt] from lanes l%16==0
    {
      int x = __builtin_amdgcn_update_dpp(0, __float_as_int(post), 0x128, 0xF, 0xF, true); // row_ror:8
      if (!(l & 15)) b16[nxt][g * 4 + (l >> 4)] = pack_pkrtz(post, __int_as_float(x));
    }

    // per-wave sum of post -> ps16[nxt] (f16; any block-uniform scale works — k_out renormalizes)
    {
      float w = post;
      w = dpp_add<0x128>(w);
      w = dpp_add<0x142>(w);
      w = dpp_add<0x143>(w);
      if (l == 48) ps16[nxt][g] = (unsigned short)(pack_pkrtz(w, 0.f) & 0xffffu);
    }

    // rotate pa
    #define CPPA(A) pac_##A = pan_##A;
    FOR16(CPPA)

    BAR();
    cur = nxt;
  }
}

// ---------------- epilogue: logp_pi + logp_obs, fully parallel over (t,n) ----------------
__global__ __launch_bounds__(128, 1) void k_out(const float* __restrict__ bseq,
                                                const float* __restrict__ Qg,
                                                const float* __restrict__ lo,
                                                const float* __restrict__ lu,
                                                float* __restrict__ out){
  __shared__ __align__(16) float Qs[A_DIM][S_DIM];
  const int tid = threadIdx.x;
  for (int i = tid; i < A_DIM * S_DIM; i += 128) Qs[i >> 6][i & 63] = Qg[i];
  __syncthreads();

  const int item = blockIdx.x * 128 + tid;   // t*64 + n
  float bs[64];
  const float* bp_ = bseq + item * 64;
  float bsum = 0.f;
  #pragma unroll
  for (int i = 0; i < 16; ++i){
    float4 v = *(const float4*)(bp_ + 4 * i);
    bs[4*i] = v.x; bs[4*i+1] = v.y; bs[4*i+2] = v.z; bs[4*i+3] = v.w;
    bsum += (v.x + v.y) + (v.z + v.w);
  }
  float binv = 1.0f / bsum;

  float G[A_DIM];
  #pragma unroll
  for (int a = 0; a < A_DIM; ++a){
    float acc = 0.f;
    #pragma unroll
    for (int s = 0; s < 64; ++s) acc = fmaf(bs[s], Qs[a][s], acc);
    G[a] = acc * binv;
  }
  const float* lup = lu + item * A_DIM;
  float m1 = -1e30f, m0 = -1e30f;
  float x1[A_DIM];
  #pragma unroll
  for (int a = 0; a < A_DIM; ++a){
    x1[a] = G[a] + lup[a];
    m1 = fmaxf(m1, x1[a]);
    m0 = fmaxf(m0, G[a]);
  }
  float e1 = 0.f, e0 = 0.f;
  #pragma unroll
  for (int a = 0; a < A_DIM; ++a){
    e1 += __expf(x1[a] - m1);
    e0 += __expf(G[a] - m0);
  }
  out[item] = (m1 + __logf(e1)) - (m0 + __logf(e0));

  // logp_obs: uses b[t+1] and lo[t]
  const float* bq = bseq + (item + 64) * 64;
  float bsum2 = 0.f;
  #pragma unroll
  for (int i = 0; i < 16; ++i){
    float4 v = *(const float4*)(bq + 4 * i);
    bs[4*i] = v.x; bs[4*i+1] = v.y; bs[4*i+2] = v.z; bs[4*i+3] = v.w;
    bsum2 += (v.x + v.y) + (v.z + v.w);
  }
  float inv2 = 1.0f / bsum2;
  const float* lop = lo + item * 64;
  float terms[64];
  float mt = -1e30f;
  #pragma unroll
  for (int i = 0; i < 16; ++i){
    float4 v = *(const float4*)(lop + 4 * i);
    float t0 = __logf(bs[4*i]   * inv2 + 1e-6f) * v.x;
    float t1 = __logf(bs[4*i+1] * inv2 + 1e-6f) * v.y;
    float t2 = __logf(bs[4*i+2] * inv2 + 1e-6f) * v.z;
    float t3 = __logf(bs[4*i+3] * inv2 + 1e-6f) * v.w;
    terms[4*i] = t0; terms[4*i+1] = t1; terms[4*i+2] = t2; terms[4*i+3] = t3;
    mt = fmaxf(mt, fmaxf(fmaxf(t0, t1), fmaxf(t2, t3)));
  }
  float es = 0.f;
  #pragma unroll
  for (int s = 0; s < 64; ++s) es += __expf(terms[s] - mt);
  out[T_STEPS * BATCH + item] = mt + __logf(es);
}

extern "C" void kernel_launch(void* const* d_in, const int* in_sizes, int n_in,
                              void* d_out, int out_size, void* d_ws, size_t ws_size,
                              hipStream_t stream){
  const float* o      = (const float*)d_in[0];
  const float* u      = (const float*)d_in[1];
  const float* obs_mu = (const float*)d_in[2];
  const float* obs_lv = (const float*)d_in[3];
  const float* obs_tl = (const float*)d_in[4];
  const float* ctl_mu = (const float*)d_in[5];
  const float* ctl_lv = (const float*)d_in[6];
  const float* ctl_tl = (const float*)d_in[7];
  const float* Blog   = (const float*)d_in[8];
  const float* Dlog   = (const float*)d_in[9];
  const float* Clog   = (const float*)d_in[10];
  const float* tau    = (const float*)d_in[11];
  float* out = (float*)d_out;
  float* ws  = (float*)d_ws;

  _Float16* Bph = (_Float16*)ws;       // 65536 halves = 32768 f32 slots ([a][j][s])
  float* Q    = ws + 32768;            // 1024
  float* lo   = ws + 33792;            // 2,048,000
  float* lu   = ws + 2081792;          // 512,000
  float* pa   = ws + 2593792;          // 512,000
  float* bseq = ws + 3105792;          // 501*4096 = 2,052,096   (total ~20.6 MiB)

  k_front<<<2145, 1024, 0, stream>>>(o, obs_mu, obs_lv, obs_tl, Blog,
                                     u, ctl_mu, ctl_lv, ctl_tl, Clog, tau,
                                     lo, Bph, lu, pa, Q);
  k_scan <<<dim3(64, CHUNKS), 512, 0, stream>>>(Bph, lo, pa, Dlog, bseq);
  k_out  <<<250, 128, 0, stream>>>(bseq, Q, lo, lu, out);
}